// Round 10
// baseline (28991.986 us; speedup 1.0000x reference)
//
#include <hip/hip_runtime.h>
#include <math.h>

// ---------------- problem constants ----------------
// B=12, T=2048, D=260, V=256, R=280, 3D=780
// k23: wid<60  -> scan1 role, 12 groups x 5 WGs (flag protocol)
//      wid>=60 -> scan2 role, 12 groups x 9 WGs (tagged 8B mailbox,
//                 per-wave dims, ONE barrier per round)

// ---------------- workspace layout (float offsets) ----------------
#define OFF_XTAB  0            // [256][780]
#define OFF_KEYS  199680       // [280][260]
#define OFF_SNT   272480       // [260][256]
#define OFF_PFCT  339040       // [520][260]
#define OFF_PF    474240       // [2048][12][260] p_f, overlaid by latf
#define OFF_OUTS  6864000      // [12][2048][260] outs (head = ctl during scans)
#define OFF_HBUF  13253760     // [2][12][260] scan1 h mailbox (flag protocol)
#define OFF_HMT   13260000     // [2][12][260] x 8B tagged hm slots
#define OFF_WILL  13272480     // will accumulator
#define WS_FLOATS 13272544

// ctl at OFF_OUTS: scan1 flags 12*5*32=1920 ints; poison at [1984]
#define CTL_POISON 1984
#define CTL_INTS   2048

// ---------------- output layout (float offsets) ----------------
#define OUT_HF 6291456
#define OUT_HM 6294576
#define OUT_DS 6297696

// ---- proven write-through 4B ops (relaxed agent atomics) ----
__device__ inline void st_wt(float* p, float v) {
  __hip_atomic_store(p, v, __ATOMIC_RELAXED, __HIP_MEMORY_SCOPE_AGENT);
}
__device__ inline float ld_wt(const float* p) {
  return __hip_atomic_load(p, __ATOMIC_RELAXED, __HIP_MEMORY_SCOPE_AGENT);
}
__device__ inline int ld_agi(const int* p) {
  return __hip_atomic_load(p, __ATOMIC_RELAXED, __HIP_MEMORY_SCOPE_AGENT);
}
__device__ inline void st_agi(int* p, int v) {
  __hip_atomic_store(p, v, __ATOMIC_RELAXED, __HIP_MEMORY_SCOPE_AGENT);
}

// ---- 8B tagged mailbox ops (sc1 = agent scope), R9-proven ----
__device__ inline void store_tag(unsigned long long* slot, float v, int tag) {
  union { float f; unsigned int u; } c; c.f = v;
  unsigned long long pv = ((unsigned long long)(unsigned int)tag << 32) | (unsigned long long)c.u;
  asm volatile("global_store_dwordx2 %0, %1, off sc1" :: "v"(slot), "v"(pv) : "memory");
}
__device__ inline float poll_tag(const unsigned long long* slot, int want, int* poison) {
  unsigned long long pv; int spins = 0;
  for (;;) {
    asm volatile("global_load_dwordx2 %0, %1, off sc1\n\ts_waitcnt vmcnt(0)"
                 : "=v"(pv) : "v"(slot) : "memory");
    if ((int)(pv >> 32) >= want) break;
    if ((++spins & 255) == 0) {
      if (ld_agi(poison)) break;
      if (spins >= 4096) { st_agi(poison, 1); break; }
    }
  }
  union { unsigned int u; float f; } c; c.u = (unsigned int)pv;
  return c.f;
}
__device__ inline void poll_flag(const int* fp, int target, int* poison) {
  int spins = 0;
  while (ld_agi(fp) < target) {
    if ((++spins & 255) == 0) {
      if (ld_agi(poison)) break;
      if (spins >= 4096) { st_agi(poison, 1); break; }
    }
  }
}

__device__ inline float block_sum256(float v, float* red) {
  #pragma unroll
  for (int m = 32; m; m >>= 1) v += __shfl_xor(v, m);
  int w = threadIdx.x >> 6;
  __syncthreads();
  if ((threadIdx.x & 63) == 0) red[w] = v;
  __syncthreads();
  return red[0] + red[1] + red[2] + red[3];
}

// scan1 barrier (proven): post my flag, poll my group's 5 flags (capped)
__device__ inline void s1_post_wait(int* fl, int* poison, int sub, int target, bool skip) {
  __syncthreads();
  int tid = threadIdx.x;
  if (tid == 0) {
    asm volatile("s_waitcnt vmcnt(0)" ::: "memory");
    st_agi(fl + sub*32, target);
  }
  if (!skip) {
    if (tid < 5) poll_flag(fl + tid*32, target, poison);
    __syncthreads();
  }
}

// ============ K0: prep tables ============
__global__ __launch_bounds__(256) void k0_prep(
    const float* __restrict__ soma_w, const float* __restrict__ gWih,
    const float* __restrict__ gbih, const float* __restrict__ rel_keys,
    const float* __restrict__ pfc_W, float* __restrict__ ws) {
  int bid = blockIdx.x, tid = threadIdx.x;
  __shared__ float row[260];
  __shared__ float red[4];
  if (bid < 256) {
    int v = bid;
    row[tid] = soma_w[v*260 + tid];
    if (tid < 4) row[256+tid] = soma_w[v*260 + 256 + tid];
    __syncthreads();
    for (int n = tid; n < 780; n += 256) {
      const float* w = gWih + n*260;
      float acc = gbih[n];
      for (int k = 0; k < 260; ++k) acc += row[k]*w[k];
      ws[OFF_XTAB + v*780 + n] = acc;
    }
  } else if (bid < 536) {
    int r = bid - 256;
    row[tid] = rel_keys[r*260 + tid];
    if (tid < 4) row[256+tid] = rel_keys[r*260 + 256 + tid];
    __syncthreads();
    float v0 = row[tid], v1 = (tid < 4) ? row[256+tid] : 0.f;
    float ss = block_sum256(v0*v0 + v1*v1, red);
    float sc = 1.f / fmaxf(sqrtf(ss), 1e-12f);
    ws[OFF_KEYS + r*260 + tid] = v0*sc;
    if (tid < 4) ws[OFF_KEYS + r*260 + 256 + tid] = v1*sc;
  } else if (bid < 792) {
    int v = bid - 536;
    row[tid] = soma_w[v*260 + tid];
    if (tid < 4) row[256+tid] = soma_w[v*260 + 256 + tid];
    __syncthreads();
    float v0 = row[tid], v1 = (tid < 4) ? row[256+tid] : 0.f;
    float ss = block_sum256(v0*v0 + v1*v1, red);
    float sc = 1.f / fmaxf(sqrtf(ss), 1e-12f);
    ws[OFF_SNT + tid*256 + v] = v0*sc;
    if (tid < 4) ws[OFF_SNT + (256+tid)*256 + v] = v1*sc;
  } else {
    int kk = bid - 792;
    for (int d = tid; d < 260; d += 256)
      ws[OFF_PFCT + kk*260 + d] = pfc_W[d*520 + kk];
  }
}

// ============ K23: fused scan1 + scan2 ============
__global__ __launch_bounds__(1024) void k23_scans(
    const int* __restrict__ x, const float* __restrict__ h_f,
    const float* __restrict__ gWhh, const float* __restrict__ gbhh,
    const float* __restrict__ h_mono, const float* __restrict__ wWih,
    const float* __restrict__ wWhh, const float* __restrict__ wbih,
    const float* __restrict__ wbhh, const float* __restrict__ vgW,
    const float* __restrict__ vgb, const int* __restrict__ surprise,
    const int* __restrict__ dsteps, float* __restrict__ ws,
    int* __restrict__ ctl, float* __restrict__ will_acc,
    float* __restrict__ out) {
  int wid = blockIdx.x, tid = threadIdx.x;
  float* pf = ws + OFF_PF;
  int* poison = ctl + CTL_POISON;

  if (wid < 60) {
    // ---------------- scan1 role (R8/R9-proven) ----------------
    int b = wid / 5, sub = wid - b*5;
    int d0 = sub*52;
    int* fl = ctl + b*(5*32);
    int grp = tid >> 4, l16 = tid & 15;
    int klo = l16*17;
    bool act = grp < 52;
    int dd = d0 + (act ? grp : 0);
    float w1[3][17];
    #pragma unroll
    for (int gg = 0; gg < 3; ++gg) {
      const float* wr = gWhh + (gg*260 + dd)*260;
      #pragma unroll
      for (int kk = 0; kk < 17; ++kk) {
        int k = klo + kk;
        w1[gg][kk] = (act && k < 260) ? wr[k] : 0.f;
      }
    }
    __shared__ float hsh[320];
    __shared__ float gl[52][3];
    __shared__ float bhh_l[52][3];
    if (tid >= 260 && tid < 320) hsh[tid] = 0.f;
    if (tid < 156) {
      int dl = tid/3, g2 = tid - dl*3;
      bhh_l[dl][g2] = gbhh[g2*260 + d0 + dl];
    }
    float* hbuf = ws + OFF_HBUF;
    const float* xtab = ws + OFF_XTAB;
    int p = 0;
    __syncthreads();
    for (int t = 0; t < 2048; ++t) {
      if (t == 0) {
        if (tid < 260) hsh[tid] = h_f[b*260 + tid];
      } else {
        if (tid < 260) hsh[tid] = ld_wt(hbuf + p*3120 + b*260 + tid);
      }
      __syncthreads();
      if (act) {
        float a0 = 0.f, a1 = 0.f, a2 = 0.f;
        const float* hp = &hsh[klo];
        #pragma unroll
        for (int kk = 0; kk < 17; ++kk) {
          float hv = hp[kk];
          a0 += w1[0][kk]*hv; a1 += w1[1][kk]*hv; a2 += w1[2][kk]*hv;
        }
        #pragma unroll
        for (int m = 8; m; m >>= 1) {
          a0 += __shfl_xor(a0, m); a1 += __shfl_xor(a1, m); a2 += __shfl_xor(a2, m);
        }
        if (l16 == 0) { gl[grp][0] = a0; gl[grp][1] = a1; gl[grp][2] = a2; }
      }
      __syncthreads();
      if (tid < 52) {
        int d = d0 + tid;
        int xi = x[b*2048 + t];
        const float* xrow = xtab + xi*780;
        float xr = xrow[d], xz = xrow[260+d], xn = xrow[520+d];
        float hr = gl[tid][0] + bhh_l[tid][0];
        float hz = gl[tid][1] + bhh_l[tid][1];
        float hn = gl[tid][2] + bhh_l[tid][2];
        float rg = 1.f/(1.f + expf(-(xr+hr)));
        float zg = 1.f/(1.f + expf(-(xz+hz)));
        float ng = tanhf(xn + rg*hn);
        float hprev = hsh[d];
        float hnew = (1.f - zg)*ng + zg*hprev;
        st_wt(hbuf + (p^1)*3120 + b*260 + d, hnew);
        st_wt(pf + (t*12 + b)*260 + d, hnew);
        if (t == 2047) out[OUT_HF + b*260 + d] = hnew;
      }
      s1_post_wait(fl, poison, sub, t+1, t == 2047);
      p ^= 1;
    }
    return;
  }

  // ------- scan2 role: per-wave dims, one barrier per round -------
  // wave wv owns dims {2wv, 2wv+1}. lanes 0-15: Wih dim A, 16-31: Whh dim A,
  // 32-47: Wih dim B, 48-63: Whh dim B. sigma computed redundantly per wave.
  int w = wid - 60;
  int b = w / 9, sub = w - b*9;
  int d0 = sub*32;
  int ndim = (sub < 8) ? 32 : 4;
  int ds = dsteps[0];
  if (ds < 1) {
    if (sub == 0 && tid < 260) out[OUT_HM + b*260 + tid] = h_mono[b*260 + tid];
    return;
  }
  const int* fl1 = ctl + b*(5*32);
  int wv = tid >> 6, ln = tid & 63;
  int half = ln >> 5, srcg = (ln >> 4) & 1, l16 = ln & 15;
  int klo = l16*17;
  int dimloc = wv*2 + half;
  bool dact = dimloc < ndim;
  int d = d0 + (dact ? dimloc : 0);
  float w3[3][17];
  {
    const float* M = srcg ? wWhh : wWih;
    #pragma unroll
    for (int gg = 0; gg < 3; ++gg) {
      const float* wr = M + (gg*260 + d)*260;
      #pragma unroll
      for (int kk = 0; kk < 17; ++kk) {
        int k = klo + kk;
        w3[gg][kk] = (dact && k < 260) ? wr[k] : 0.f;
      }
    }
  }
  float bih0=0, bih1=0, bih2=0, bhh0=0, bhh1=0, bhh2=0;
  if (dact) {
    bih0 = wbih[d]; bih1 = wbih[260+d]; bih2 = wbih[520+d];
    bhh0 = wbhh[d]; bhh1 = wbhh[260+d]; bhh2 = wbhh[520+d];
  }
  __shared__ float hmsh[2][320];
  __shared__ float vsh2[2][320];
  __shared__ float vgsh[320];
  if (tid < 320) {
    hmsh[0][tid] = 0.f; hmsh[1][tid] = 0.f;
    vsh2[0][tid] = 0.f; vsh2[1][tid] = 0.f;
    vgsh[tid] = (tid < 260) ? vgW[tid] : 0.f;
  }
  float A0=0, A1=0, A2=0, latv=0, sigma=0, volp=0, will_local=0;
  float sb = logf(fmaxf(1.f, (float)surprise[0]));
  float vgb_sb = vgb[0] + sb;
  unsigned long long* hmt = (unsigned long long*)(ws + OFF_HMT);
  __syncthreads();
  for (int t = 0; t < 2048; ++t) {
    for (int s = 0; s < ds; ++s) {
      int r = t*ds + s;
      // ---- staging: hm poll (+pf at s==0) into double-buffered LDS ----
      if (r == 0) {
        if (tid < 260) hmsh[0][tid] = h_mono[b*260 + tid];
      } else {
        if (tid < 260)
          hmsh[r&1][tid] = poll_tag(hmt + ((r&1)*12 + b)*260 + tid, r, poison);
      }
      if (s == 0 && tid >= 512 && tid < 772) {
        int q = tid - 512;
        poll_flag(fl1 + (q % 5)*32, t+1, poison);
        vsh2[t&1][q] = ld_wt(pf + (t*12 + b)*260 + q);
      }
      __syncthreads();                 // the ONE barrier of the round
      const float* hv = hmsh[r&1];
      const float* vv = vsh2[t&1];
      // ---- dots (all 64 lanes; 16-lane shuffle reduce, order-identical) ----
      const float* S = (srcg == 0 && s == 0) ? vv : hv;
      const float* sp = &S[klo];
      float a0 = 0.f, a1 = 0.f, a2 = 0.f;
      #pragma unroll
      for (int kk = 0; kk < 17; ++kk) {
        float v = sp[kk];
        a0 += w3[0][kk]*v; a1 += w3[1][kk]*v; a2 += w3[2][kk]*v;
      }
      #pragma unroll
      for (int m = 8; m; m >>= 1) {
        a0 += __shfl_xor(a0,m); a1 += __shfl_xor(a1,m); a2 += __shfl_xor(a2,m);
      }
      // ---- sigma/vol recurrence (redundant per wave, identical) ----
      float ph = vgsh[ln]*hv[ln] + vgsh[ln+64]*hv[ln+64]
               + vgsh[ln+128]*hv[ln+128] + vgsh[ln+192]*hv[ln+192]
               + ((ln < 4) ? vgsh[ln+256]*hv[ln+256] : 0.f);
      #pragma unroll
      for (int m = 32; m; m >>= 1) ph += __shfl_xor(ph, m);
      if (s == 0) {
        float pp = vgsh[ln]*vv[ln] + vgsh[ln+64]*vv[ln+64]
                 + vgsh[ln+128]*vv[ln+128] + vgsh[ln+192]*vv[ln+192]
                 + ((ln < 4) ? vgsh[ln+256]*vv[ln+256] : 0.f);
        #pragma unroll
        for (int m = 32; m; m >>= 1) pp += __shfl_xor(pp, m);
        sigma = pp;
      } else {
        sigma += volp * ph;
      }
      float voln = 1.f/(1.f + expf(-(sigma + vgb_sb)));
      // ---- gates: pull Whh dots from the src1 half of this dim's 32 lanes ----
      int peer = (half << 5) + 16;
      float gh0 = __shfl(a0, peer);
      float gh1 = __shfl(a1, peer);
      float gh2 = __shfl(a2, peer);
      if (s == 0) { A0 = a0; A1 = a1; A2 = a2; latv = vv[d]; }
      else        { A0 += volp*a0; A1 += volp*a1; A2 += volp*a2; }
      float rg = 1.f/(1.f + expf(-((A0 + bih0) + (gh0 + bhh0))));
      float zg = 1.f/(1.f + expf(-((A1 + bih1) + (gh1 + bhh1))));
      float ng = tanhf((A2 + bih2) + rg*(gh2 + bhh2));
      float hmo = hv[d];
      float hmn = (1.f - zg)*ng + zg*hmo;
      latv += hmn * voln;
      if (dact && srcg == 0 && l16 == 0) {
        store_tag(hmt + (((r+1)&1)*12 + b)*260 + d, hmn, r+1);
        if (s == ds-1) {
          pf[(t*12 + b)*260 + d] = latv;     // latf overlay (k4 reads post-boundary)
          if (t == 2047) out[OUT_HM + b*260 + d] = hmn;
        }
      }
      if (sub == 0 && tid == 0) will_local += voln;
      volp = voln;
    }
  }
  if (sub == 0 && tid == 0) atomicAdd(will_acc, will_local);
}

// ============ K4: per-t tail + scalars ============
__global__ __launch_bounds__(256) void k4_tail(
    const float* __restrict__ rel_vals, const float* __restrict__ pfc_b,
    const float* __restrict__ pfc_g, const float* __restrict__ pfc_beta,
    const int* __restrict__ dsteps, const float* __restrict__ will_acc,
    float* __restrict__ ws, float* __restrict__ out) {
  int t = blockIdx.x, tid = threadIdx.x;
  int tg = tid >> 4, l16 = tid & 15;
  if (t == 0 && tid == 0) {
    int ds = dsteps[0]; int dsm = ds < 1 ? 1 : ds;
    float W = will_acc[0] * (1.f/12.f);
    out[OUT_DS]   = (float)ds;
    out[OUT_DS+1] = W * (0.12f/2048.f);
    out[OUT_DS+2] = W / (2048.f * (float)dsm);
  }
  __shared__ float lat[12][260];
  __shared__ float sc[12][280];
  __shared__ float ctx[12][260];
  __shared__ float zb[12][260];
  __shared__ float qinv[12];
  __shared__ float mu[12], rstd[12];
  const float* lsrc = ws + OFF_PF + t*3120;
  for (int idx = tid; idx < 780; idx += 256)
    ((float4*)lat)[idx] = ((const float4*)lsrc)[idx];
  __syncthreads();
  if (tg < 12) {
    float ss = 0;
    for (int k = l16; k < 260; k += 16) { float v = lat[tg][k]; ss += v*v; }
    #pragma unroll
    for (int m = 8; m; m >>= 1) ss += __shfl_xor(ss, m);
    if (l16 == 0) qinv[tg] = 1.f / fmaxf(sqrtf(ss), 1e-12f);
  }
  __syncthreads();
  for (int r = tid; r < 280; r += 256) {
    const float* kn = ws + OFF_KEYS + r*260;
    float acc[12];
    #pragma unroll
    for (int i = 0; i < 12; ++i) acc[i] = 0.f;
    for (int k = 0; k < 260; ++k) {
      float kv = kn[k];
      #pragma unroll
      for (int i = 0; i < 12; ++i) acc[i] += lat[i][k]*kv;
    }
    #pragma unroll
    for (int i = 0; i < 12; ++i) sc[i][r] = acc[i]*qinv[i];
  }
  __syncthreads();
  if (tg < 12) {
    float mx = -1e30f;
    for (int r = l16; r < 280; r += 16) mx = fmaxf(mx, sc[tg][r]);
    #pragma unroll
    for (int m = 8; m; m >>= 1) mx = fmaxf(mx, __shfl_xor(mx, m));
    float sum = 0;
    for (int r = l16; r < 280; r += 16) { float e = expf(sc[tg][r]-mx); sc[tg][r] = e; sum += e; }
    #pragma unroll
    for (int m = 8; m; m >>= 1) sum += __shfl_xor(sum, m);
    float inv = 1.f/sum;
    for (int r = l16; r < 280; r += 16) sc[tg][r] *= inv;
  }
  __syncthreads();
  for (int dd = tid; dd < 260; dd += 256) {
    float acc[12];
    #pragma unroll
    for (int i = 0; i < 12; ++i) acc[i] = 0.f;
    for (int r = 0; r < 280; ++r) {
      float rv = rel_vals[r*260 + dd];
      #pragma unroll
      for (int i = 0; i < 12; ++i) acc[i] += sc[i][r]*rv;
    }
    #pragma unroll
    for (int i = 0; i < 12; ++i) ctx[i][dd] = acc[i];
  }
  __syncthreads();
  for (int dd = tid; dd < 260; dd += 256) {
    float acc[12];
    float pb = pfc_b[dd];
    #pragma unroll
    for (int i = 0; i < 12; ++i) acc[i] = pb;
    const float* wt = ws + OFF_PFCT;
    for (int k = 0; k < 260; ++k) {
      float w1 = wt[k*260 + dd];
      #pragma unroll
      for (int i = 0; i < 12; ++i) acc[i] += lat[i][k]*w1;
    }
    for (int k = 0; k < 260; ++k) {
      float w2 = wt[(260+k)*260 + dd];
      #pragma unroll
      for (int i = 0; i < 12; ++i) acc[i] += ctx[i][k]*w2;
    }
    #pragma unroll
    for (int i = 0; i < 12; ++i) zb[i][dd] = acc[i];
  }
  __syncthreads();
  if (tg < 12) {
    float s1 = 0, s2 = 0;
    for (int k = l16; k < 260; k += 16) { float v = zb[tg][k]; s1 += v; s2 += v*v; }
    #pragma unroll
    for (int m = 8; m; m >>= 1) { s1 += __shfl_xor(s1,m); s2 += __shfl_xor(s2,m); }
    if (l16 == 0) {
      float mm = s1*(1.f/260.f);
      mu[tg] = mm;
      rstd[tg] = rsqrtf(s2*(1.f/260.f) - mm*mm + 1e-5f);
    }
  }
  __syncthreads();
  for (int dd = tid; dd < 260; dd += 256) {
    float g = pfc_g[dd], b = pfc_beta[dd];
    #pragma unroll
    for (int i = 0; i < 12; ++i) {
      float v = (zb[i][dd]-mu[i])*rstd[i]*g + b;
      float ge = 0.5f*v*(1.f + erff(v*0.70710678118654752f));
      ws[OFF_OUTS + (i*2048 + t)*260 + dd] = ge;
    }
  }
}

// ============ K5: fused LN + logits GEMM ============
__global__ __launch_bounds__(256) void k5_logits(
    const float* __restrict__ on_g, const float* __restrict__ on_b,
    const float* __restrict__ gain, float* __restrict__ ws,
    float* __restrict__ out) {
  int bid = blockIdx.x, tid = threadIdx.x;
  __shared__ float nl[8][260];
  __shared__ float red[4];
  float gn = gain[0];
  float og0 = on_g[tid], ob0 = on_b[tid];
  float og1 = (tid < 4) ? on_g[256+tid] : 0.f;
  float ob1 = (tid < 4) ? on_b[256+tid] : 0.f;
  for (int ii = 0; ii < 8; ++ii) {
    int m = bid*8 + ii;
    const float* row = ws + OFF_OUTS + m*260;
    float v0 = row[tid];
    float v1 = (tid < 4) ? row[256+tid] : 0.f;
    float s1 = block_sum256(v0 + v1, red);
    float s2 = block_sum256(v0*v0 + v1*v1, red);
    float mm = s1*(1.f/260.f);
    float rs = rsqrtf(s2*(1.f/260.f) - mm*mm + 1e-5f);
    nl[ii][tid] = (v0-mm)*rs*og0 + ob0;
    if (tid < 4) nl[ii][256+tid] = (v1-mm)*rs*og1 + ob1;
  }
  __syncthreads();
  float acc[8];
  #pragma unroll
  for (int ii = 0; ii < 8; ++ii) acc[ii] = 0.f;
  const float* st = ws + OFF_SNT;
  for (int k = 0; k < 260; ++k) {
    float wv = st[k*256 + tid];
    #pragma unroll
    for (int ii = 0; ii < 8; ++ii) acc[ii] += nl[ii][k]*wv;
  }
  #pragma unroll
  for (int ii = 0; ii < 8; ++ii)
    out[(bid*8 + ii)*256 + tid] = acc[ii]*gn;
}

// ============================ launch ============================
extern "C" void kernel_launch(void* const* d_in, const int* in_sizes, int n_in,
                              void* d_out, int out_size, void* d_ws, size_t ws_size,
                              hipStream_t stream) {
  const int*   x        = (const int*)  d_in[0];
  const float* h_f      = (const float*)d_in[1];
  const float* h_mono   = (const float*)d_in[2];
  const int*   surprise = (const int*)  d_in[3];
  const int*   dsteps   = (const int*)  d_in[4];
  const float* soma_w   = (const float*)d_in[5];
  const float* gWih     = (const float*)d_in[6];
  const float* gWhh     = (const float*)d_in[7];
  const float* gbih     = (const float*)d_in[8];
  const float* gbhh     = (const float*)d_in[9];
  const float* wWih     = (const float*)d_in[10];
  const float* wWhh     = (const float*)d_in[11];
  const float* wbih     = (const float*)d_in[12];
  const float* wbhh     = (const float*)d_in[13];
  const float* vgW      = (const float*)d_in[14];
  const float* vgb      = (const float*)d_in[15];
  const float* rel_keys = (const float*)d_in[16];
  const float* rel_vals = (const float*)d_in[17];
  const float* pfc_W    = (const float*)d_in[18];
  const float* pfc_b    = (const float*)d_in[19];
  const float* pfc_g    = (const float*)d_in[20];
  const float* pfc_beta = (const float*)d_in[21];
  const float* on_g     = (const float*)d_in[22];
  const float* on_b     = (const float*)d_in[23];
  const float* gain     = (const float*)d_in[24];
  float* out = (float*)d_out;
  float* ws  = (float*)d_ws;
  if (ws_size < (size_t)WS_FLOATS * sizeof(float)) return;  // fail loudly (poisoned out)
  int*   ctl      = (int*)(ws + OFF_OUTS);       // dead during scans; k4 rewrites
  float* will_acc = ws + OFF_WILL;
  hipMemsetAsync(ctl, 0, CTL_INTS*sizeof(int), stream);
  hipMemsetAsync(ws + OFF_HMT, 0, (size_t)(WS_FLOATS - OFF_HMT)*sizeof(float), stream);
  k0_prep  <<<1312, 256, 0, stream>>>(soma_w, gWih, gbih, rel_keys, pfc_W, ws);
  k23_scans<<<168, 1024, 0, stream>>>(x, h_f, gWhh, gbhh, h_mono, wWih, wWhh,
                                      wbih, wbhh, vgW, vgb, surprise, dsteps,
                                      ws, ctl, will_acc, out);
  k4_tail  <<<2048, 256, 0, stream>>>(rel_vals, pfc_b, pfc_g, pfc_beta,
                                      dsteps, will_acc, ws, out);
  k5_logits<<<3072, 256, 0, stream>>>(on_g, on_b, gain, ws, out);
}

// Round 12
// 23127.577 us; speedup vs baseline: 1.2536x; 1.2536x over previous
//
#include <hip/hip_runtime.h>
#include <math.h>

// ---------------- problem constants ----------------
// B=12, T=2048, D=260, V=256, R=280, 3D=780
// k23: wid<60  -> scan1 role, 12 groups x 5 WGs (flag protocol, proven)
//      wid>=60 -> scan2 role, 12 groups x 9 WGs (tagged 8B mailbox,
//                 dbuf LDS, TWO barriers per round)

// ---------------- workspace layout (float offsets) ----------------
#define OFF_XTAB  0            // [256][780]
#define OFF_KEYS  199680       // [280][260]
#define OFF_SNT   272480       // [260][256]
#define OFF_PFCT  339040       // [520][260]
#define OFF_PF    474240       // [2048][12][260] p_f, overlaid by latf
#define OFF_OUTS  6864000      // [12][2048][260] outs (head = ctl during scans)
#define OFF_HBUF  13253760     // [2][12][260] scan1 h mailbox (flag protocol)
#define OFF_HMT   13260000     // [2][12][260] x 8B tagged hm slots
#define OFF_WILL  13272480     // will accumulator
#define WS_FLOATS 13272544

// ctl at OFF_OUTS: scan1 flags 12*5*32=1920 ints; poison at [1984]
#define CTL_POISON 1984
#define CTL_INTS   2048

// ---------------- output layout (float offsets) ----------------
#define OUT_HF 6291456
#define OUT_HM 6294576
#define OUT_DS 6297696

// ---- proven write-through 4B ops (relaxed agent atomics) ----
__device__ inline void st_wt(float* p, float v) {
  __hip_atomic_store(p, v, __ATOMIC_RELAXED, __HIP_MEMORY_SCOPE_AGENT);
}
__device__ inline float ld_wt(const float* p) {
  return __hip_atomic_load(p, __ATOMIC_RELAXED, __HIP_MEMORY_SCOPE_AGENT);
}
__device__ inline int ld_agi(const int* p) {
  return __hip_atomic_load(p, __ATOMIC_RELAXED, __HIP_MEMORY_SCOPE_AGENT);
}
__device__ inline void st_agi(int* p, int v) {
  __hip_atomic_store(p, v, __ATOMIC_RELAXED, __HIP_MEMORY_SCOPE_AGENT);
}

// ---- 8B tagged mailbox ops (sc1 = agent scope), R9-proven ----
__device__ inline void store_tag(unsigned long long* slot, float v, int tag) {
  union { float f; unsigned int u; } c; c.f = v;
  unsigned long long pv = ((unsigned long long)(unsigned int)tag << 32) | (unsigned long long)c.u;
  asm volatile("global_store_dwordx2 %0, %1, off sc1" :: "v"(slot), "v"(pv) : "memory");
}
__device__ inline float poll_tag(const unsigned long long* slot, int want, int* poison) {
  unsigned long long pv; int spins = 0;
  for (;;) {
    asm volatile("global_load_dwordx2 %0, %1, off sc1\n\ts_waitcnt vmcnt(0)"
                 : "=v"(pv) : "v"(slot) : "memory");
    if ((int)(pv >> 32) >= want) break;
    if ((++spins & 255) == 0) {
      if (ld_agi(poison)) break;
      if (spins >= (1 << 20)) { st_agi(poison, 1); break; }
    }
  }
  union { unsigned int u; float f; } c; c.u = (unsigned int)pv;
  return c.f;
}
__device__ inline void poll_flag(const int* fp, int target, int* poison) {
  int spins = 0;
  while (ld_agi(fp) < target) {
    if ((++spins & 255) == 0) {
      if (ld_agi(poison)) break;
      if (spins >= (1 << 20)) { st_agi(poison, 1); break; }
    }
  }
}

__device__ inline float block_sum256(float v, float* red) {
  #pragma unroll
  for (int m = 32; m; m >>= 1) v += __shfl_xor(v, m);
  int w = threadIdx.x >> 6;
  __syncthreads();
  if ((threadIdx.x & 63) == 0) red[w] = v;
  __syncthreads();
  return red[0] + red[1] + red[2] + red[3];
}

// scan1 barrier (proven)
__device__ inline void s1_post_wait(int* fl, int* poison, int sub, int target, bool skip) {
  __syncthreads();
  int tid = threadIdx.x;
  if (tid == 0) {
    asm volatile("s_waitcnt vmcnt(0)" ::: "memory");
    st_agi(fl + sub*32, target);
  }
  if (!skip) {
    if (tid < 5) poll_flag(fl + tid*32, target, poison);
    __syncthreads();
  }
}

// ============ K0: prep tables ============
__global__ __launch_bounds__(256) void k0_prep(
    const float* __restrict__ soma_w, const float* __restrict__ gWih,
    const float* __restrict__ gbih, const float* __restrict__ rel_keys,
    const float* __restrict__ pfc_W, float* __restrict__ ws) {
  int bid = blockIdx.x, tid = threadIdx.x;
  __shared__ float row[260];
  __shared__ float red[4];
  if (bid < 256) {
    int v = bid;
    row[tid] = soma_w[v*260 + tid];
    if (tid < 4) row[256+tid] = soma_w[v*260 + 256 + tid];
    __syncthreads();
    for (int n = tid; n < 780; n += 256) {
      const float* w = gWih + n*260;
      float acc = gbih[n];
      for (int k = 0; k < 260; ++k) acc += row[k]*w[k];
      ws[OFF_XTAB + v*780 + n] = acc;
    }
  } else if (bid < 536) {
    int r = bid - 256;
    row[tid] = rel_keys[r*260 + tid];
    if (tid < 4) row[256+tid] = rel_keys[r*260 + 256 + tid];
    __syncthreads();
    float v0 = row[tid], v1 = (tid < 4) ? row[256+tid] : 0.f;
    float ss = block_sum256(v0*v0 + v1*v1, red);
    float sc = 1.f / fmaxf(sqrtf(ss), 1e-12f);
    ws[OFF_KEYS + r*260 + tid] = v0*sc;
    if (tid < 4) ws[OFF_KEYS + r*260 + 256 + tid] = v1*sc;
  } else if (bid < 792) {
    int v = bid - 536;
    row[tid] = soma_w[v*260 + tid];
    if (tid < 4) row[256+tid] = soma_w[v*260 + 256 + tid];
    __syncthreads();
    float v0 = row[tid], v1 = (tid < 4) ? row[256+tid] : 0.f;
    float ss = block_sum256(v0*v0 + v1*v1, red);
    float sc = 1.f / fmaxf(sqrtf(ss), 1e-12f);
    ws[OFF_SNT + tid*256 + v] = v0*sc;
    if (tid < 4) ws[OFF_SNT + (256+tid)*256 + v] = v1*sc;
  } else {
    int kk = bid - 792;
    for (int d = tid; d < 260; d += 256)
      ws[OFF_PFCT + kk*260 + d] = pfc_W[d*520 + kk];
  }
}

// ============ K23: fused scan1 + scan2 ============
__global__ __launch_bounds__(1024) void k23_scans(
    const int* __restrict__ x, const float* __restrict__ h_f,
    const float* __restrict__ gWhh, const float* __restrict__ gbhh,
    const float* __restrict__ h_mono, const float* __restrict__ wWih,
    const float* __restrict__ wWhh, const float* __restrict__ wbih,
    const float* __restrict__ wbhh, const float* __restrict__ vgW,
    const float* __restrict__ vgb, const int* __restrict__ surprise,
    const int* __restrict__ dsteps, float* __restrict__ ws,
    int* __restrict__ ctl, float* __restrict__ will_acc,
    float* __restrict__ out) {
  int wid = blockIdx.x, tid = threadIdx.x;
  float* pf = ws + OFF_PF;
  int* poison = ctl + CTL_POISON;

  if (wid < 60) {
    // ---------------- scan1 role (R8/R9-proven, unchanged) ----------------
    int b = wid / 5, sub = wid - b*5;
    int d0 = sub*52;
    int* fl = ctl + b*(5*32);
    int grp = tid >> 4, l16 = tid & 15;
    int klo = l16*17;
    bool act = grp < 52;
    int dd = d0 + (act ? grp : 0);
    float w1[3][17];
    #pragma unroll
    for (int gg = 0; gg < 3; ++gg) {
      const float* wr = gWhh + (gg*260 + dd)*260;
      #pragma unroll
      for (int kk = 0; kk < 17; ++kk) {
        int k = klo + kk;
        w1[gg][kk] = (act && k < 260) ? wr[k] : 0.f;
      }
    }
    __shared__ float hsh[320];
    __shared__ float gl[52][3];
    __shared__ float bhh_l[52][3];
    if (tid >= 260 && tid < 320) hsh[tid] = 0.f;
    if (tid < 156) {
      int dl = tid/3, g2 = tid - dl*3;
      bhh_l[dl][g2] = gbhh[g2*260 + d0 + dl];
    }
    float* hbuf = ws + OFF_HBUF;
    const float* xtab = ws + OFF_XTAB;
    int p = 0;
    __syncthreads();
    for (int t = 0; t < 2048; ++t) {
      if (t == 0) {
        if (tid < 260) hsh[tid] = h_f[b*260 + tid];
      } else {
        if (tid < 260) hsh[tid] = ld_wt(hbuf + p*3120 + b*260 + tid);
      }
      __syncthreads();
      if (act) {
        float a0 = 0.f, a1 = 0.f, a2 = 0.f;
        const float* hp = &hsh[klo];
        #pragma unroll
        for (int kk = 0; kk < 17; ++kk) {
          float hv = hp[kk];
          a0 += w1[0][kk]*hv; a1 += w1[1][kk]*hv; a2 += w1[2][kk]*hv;
        }
        #pragma unroll
        for (int m = 8; m; m >>= 1) {
          a0 += __shfl_xor(a0, m); a1 += __shfl_xor(a1, m); a2 += __shfl_xor(a2, m);
        }
        if (l16 == 0) { gl[grp][0] = a0; gl[grp][1] = a1; gl[grp][2] = a2; }
      }
      __syncthreads();
      if (tid < 52) {
        int d = d0 + tid;
        int xi = x[b*2048 + t];
        const float* xrow = xtab + xi*780;
        float xr = xrow[d], xz = xrow[260+d], xn = xrow[520+d];
        float hr = gl[tid][0] + bhh_l[tid][0];
        float hz = gl[tid][1] + bhh_l[tid][1];
        float hn = gl[tid][2] + bhh_l[tid][2];
        float rg = 1.f/(1.f + expf(-(xr+hr)));
        float zg = 1.f/(1.f + expf(-(xz+hz)));
        float ng = tanhf(xn + rg*hn);
        float hprev = hsh[d];
        float hnew = (1.f - zg)*ng + zg*hprev;
        st_wt(hbuf + (p^1)*3120 + b*260 + d, hnew);
        st_wt(pf + (t*12 + b)*260 + d, hnew);
        if (t == 2047) out[OUT_HF + b*260 + d] = hnew;
      }
      s1_post_wait(fl, poison, sub, t+1, t == 2047);
      p ^= 1;
    }
    return;
  }

  // ---- scan2 role: dbuf LDS, two barriers per round (R9 + dbuf) ----
  int w = wid - 60;
  int b = w / 9, sub = w - b*9;
  int d0 = sub*32;
  int ndim = (sub < 8) ? 32 : 4;
  int ds = dsteps[0];
  if (ds < 1) {
    if (sub == 0 && tid < 260) out[OUT_HM + b*260 + tid] = h_mono[b*260 + tid];
    return;
  }
  const int* fl1 = ctl + b*(5*32);
  int grp = tid >> 4, l16 = tid & 15;
  int klo = l16*17;
  int dl = grp >> 1, src = grp & 1;
  bool act = dl < ndim;
  int dd = d0 + (act ? dl : 0);
  float w3[3][17];
  {
    const float* M = src ? wWhh : wWih;
    #pragma unroll
    for (int gg = 0; gg < 3; ++gg) {
      const float* wr = M + (gg*260 + dd)*260;
      #pragma unroll
      for (int kk = 0; kk < 17; ++kk) {
        int k = klo + kk;
        w3[gg][kk] = (act && k < 260) ? wr[k] : 0.f;
      }
    }
  }
  __shared__ float hmsh[2][320];
  __shared__ float vsh2[2][320];
  __shared__ float vgsh[320];
  __shared__ float gl6[32][2][3];
  if (tid < 320) {
    hmsh[0][tid] = 0.f; hmsh[1][tid] = 0.f;
    vsh2[0][tid] = 0.f; vsh2[1][tid] = 0.f;
    vgsh[tid] = (tid < 260) ? vgW[tid] : 0.f;
  }
  // per-lane persistent state (wave 0): biases, A, lat, sigma, volp
  float bih0=0, bih1=0, bih2=0, bhh0=0, bhh1=0, bhh2=0;
  if (tid < ndim) {
    int d = d0 + tid;
    bih0 = wbih[d]; bih1 = wbih[260+d]; bih2 = wbih[520+d];
    bhh0 = wbhh[d]; bhh1 = wbhh[260+d]; bhh2 = wbhh[520+d];
  }
  float A0=0, A1=0, A2=0, latv=0, sigma=0, volp=0, will_local=0;
  float sb = logf(fmaxf(1.f, (float)surprise[0]));
  float vgb_sb = vgb[0] + sb;
  unsigned long long* hmt = (unsigned long long*)(ws + OFF_HMT);
  __syncthreads();
  for (int t = 0; t < 2048; ++t) {
    for (int s = 0; s < ds; ++s) {
      int r = t*ds + s;
      bool last = (t == 2047) && (s == ds-1);
      // ---- staging: hm poll (+pf at s==0) into parity LDS buffers ----
      if (r == 0) {
        if (tid < 260) hmsh[0][tid] = h_mono[b*260 + tid];
      } else {
        if (tid < 260)
          hmsh[r&1][tid] = poll_tag(hmt + ((r&1)*12 + b)*260 + tid, r, poison);
      }
      if (s == 0 && tid >= 512 && tid < 772) {
        int q = tid - 512;
        poll_flag(fl1 + (q % 5)*32, t+1, poison);
        vsh2[t&1][q] = ld_wt(pf + (t*12 + b)*260 + q);
      }
      __syncthreads();                 // B1: staging complete
      const float* hv = hmsh[r&1];
      const float* vv = vsh2[t&1];
      // ---- phase A: 6 dots per dim across lane-groups ----
      if (act) {
        const float* S = (src == 0 && s == 0) ? vv : hv;
        const float* sp = &S[klo];
        float a0 = 0.f, a1 = 0.f, a2 = 0.f;
        #pragma unroll
        for (int kk = 0; kk < 17; ++kk) {
          float v = sp[kk];
          a0 += w3[0][kk]*v; a1 += w3[1][kk]*v; a2 += w3[2][kk]*v;
        }
        #pragma unroll
        for (int m = 8; m; m >>= 1) {
          a0 += __shfl_xor(a0,m); a1 += __shfl_xor(a1,m); a2 += __shfl_xor(a2,m);
        }
        if (l16 == 0) { gl6[dl][src][0]=a0; gl6[dl][src][1]=a1; gl6[dl][src][2]=a2; }
      }
      __syncthreads();                 // B2: gl6 ready
      // ---- phase B (wave 0): sigma/vol recurrence, gates, tagged store ----
      // no end-of-round barrier: next round's staging writes the OTHER parity,
      // and its poll_tag blocks on this phase's store_tag (dataflow sync).
      if (tid < 64) {
        float ph = vgsh[tid]*hv[tid] + vgsh[tid+64]*hv[tid+64]
                 + vgsh[tid+128]*hv[tid+128] + vgsh[tid+192]*hv[tid+192]
                 + ((tid < 4) ? vgsh[tid+256]*hv[tid+256] : 0.f);
        #pragma unroll
        for (int m = 32; m; m >>= 1) ph += __shfl_xor(ph, m);
        if (s == 0) {
          float pp = vgsh[tid]*vv[tid] + vgsh[tid+64]*vv[tid+64]
                   + vgsh[tid+128]*vv[tid+128] + vgsh[tid+192]*vv[tid+192]
                   + ((tid < 4) ? vgsh[tid+256]*vv[tid+256] : 0.f);
          #pragma unroll
          for (int m = 32; m; m >>= 1) pp += __shfl_xor(pp, m);
          sigma = pp;
        } else {
          sigma += volp * ph;
        }
        float voln = 1.f/(1.f + expf(-(sigma + vgb_sb)));
        if (tid < ndim) {
          int d = d0 + tid;
          float g0 = gl6[tid][0][0], g1 = gl6[tid][0][1], g2 = gl6[tid][0][2];
          if (s == 0) { A0 = g0; A1 = g1; A2 = g2; latv = vv[d]; }
          else        { A0 += volp*g0; A1 += volp*g1; A2 += volp*g2; }
          float gi0 = A0 + bih0, gi1 = A1 + bih1, gi2 = A2 + bih2;
          float gh0 = gl6[tid][1][0] + bhh0;
          float gh1 = gl6[tid][1][1] + bhh1;
          float gh2 = gl6[tid][1][2] + bhh2;
          float rg = 1.f/(1.f + expf(-(gi0+gh0)));
          float zg = 1.f/(1.f + expf(-(gi1+gh1)));
          float ng = tanhf(gi2 + rg*gh2);
          float hmo = hv[d];
          float hmn = (1.f - zg)*ng + zg*hmo;
          store_tag(hmt + (((r+1)&1)*12 + b)*260 + d, hmn, r+1);  // earliest
          latv += hmn * voln;
          if (s == ds-1) {
            pf[(t*12 + b)*260 + d] = latv;     // latf overlay (k4 reads post-boundary)
            if (t == 2047) out[OUT_HM + b*260 + d] = hmn;
          }
        }
        if (sub == 0 && tid == 0) will_local += voln;
        volp = voln;
      }
      (void)last;
    }
  }
  if (sub == 0 && tid == 0) atomicAdd(will_acc, will_local);
}

// ============ K4: per-t tail + scalars ============
__global__ __launch_bounds__(256) void k4_tail(
    const float* __restrict__ rel_vals, const float* __restrict__ pfc_b,
    const float* __restrict__ pfc_g, const float* __restrict__ pfc_beta,
    const int* __restrict__ dsteps, const float* __restrict__ will_acc,
    float* __restrict__ ws, float* __restrict__ out) {
  int t = blockIdx.x, tid = threadIdx.x;
  int tg = tid >> 4, l16 = tid & 15;
  if (t == 0 && tid == 0) {
    int ds = dsteps[0]; int dsm = ds < 1 ? 1 : ds;
    float W = will_acc[0] * (1.f/12.f);
    out[OUT_DS]   = (float)ds;
    out[OUT_DS+1] = W * (0.12f/2048.f);
    out[OUT_DS+2] = W / (2048.f * (float)dsm);
  }
  __shared__ float lat[12][260];
  __shared__ float sc[12][280];
  __shared__ float ctx[12][260];
  __shared__ float zb[12][260];
  __shared__ float qinv[12];
  __shared__ float mu[12], rstd[12];
  const float* lsrc = ws + OFF_PF + t*3120;
  for (int idx = tid; idx < 780; idx += 256)
    ((float4*)lat)[idx] = ((const float4*)lsrc)[idx];
  __syncthreads();
  if (tg < 12) {
    float ss = 0;
    for (int k = l16; k < 260; k += 16) { float v = lat[tg][k]; ss += v*v; }
    #pragma unroll
    for (int m = 8; m; m >>= 1) ss += __shfl_xor(ss, m);
    if (l16 == 0) qinv[tg] = 1.f / fmaxf(sqrtf(ss), 1e-12f);
  }
  __syncthreads();
  for (int r = tid; r < 280; r += 256) {
    const float* kn = ws + OFF_KEYS + r*260;
    float acc[12];
    #pragma unroll
    for (int i = 0; i < 12; ++i) acc[i] = 0.f;
    for (int k = 0; k < 260; ++k) {
      float kv = kn[k];
      #pragma unroll
      for (int i = 0; i < 12; ++i) acc[i] += lat[i][k]*kv;
    }
    #pragma unroll
    for (int i = 0; i < 12; ++i) sc[i][r] = acc[i]*qinv[i];
  }
  __syncthreads();
  if (tg < 12) {
    float mx = -1e30f;
    for (int r = l16; r < 280; r += 16) mx = fmaxf(mx, sc[tg][r]);
    #pragma unroll
    for (int m = 8; m; m >>= 1) mx = fmaxf(mx, __shfl_xor(mx, m));
    float sum = 0;
    for (int r = l16; r < 280; r += 16) { float e = expf(sc[tg][r]-mx); sc[tg][r] = e; sum += e; }
    #pragma unroll
    for (int m = 8; m; m >>= 1) sum += __shfl_xor(sum, m);
    float inv = 1.f/sum;
    for (int r = l16; r < 280; r += 16) sc[tg][r] *= inv;
  }
  __syncthreads();
  for (int dd = tid; dd < 260; dd += 256) {
    float acc[12];
    #pragma unroll
    for (int i = 0; i < 12; ++i) acc[i] = 0.f;
    for (int r = 0; r < 280; ++r) {
      float rv = rel_vals[r*260 + dd];
      #pragma unroll
      for (int i = 0; i < 12; ++i) acc[i] += sc[i][r]*rv;
    }
    #pragma unroll
    for (int i = 0; i < 12; ++i) ctx[i][dd] = acc[i];
  }
  __syncthreads();
  for (int dd = tid; dd < 260; dd += 256) {
    float acc[12];
    float pb = pfc_b[dd];
    #pragma unroll
    for (int i = 0; i < 12; ++i) acc[i] = pb;
    const float* wt = ws + OFF_PFCT;
    for (int k = 0; k < 260; ++k) {
      float w1 = wt[k*260 + dd];
      #pragma unroll
      for (int i = 0; i < 12; ++i) acc[i] += lat[i][k]*w1;
    }
    for (int k = 0; k < 260; ++k) {
      float w2 = wt[(260+k)*260 + dd];
      #pragma unroll
      for (int i = 0; i < 12; ++i) acc[i] += ctx[i][k]*w2;
    }
    #pragma unroll
    for (int i = 0; i < 12; ++i) zb[i][dd] = acc[i];
  }
  __syncthreads();
  if (tg < 12) {
    float s1 = 0, s2 = 0;
    for (int k = l16; k < 260; k += 16) { float v = zb[tg][k]; s1 += v; s2 += v*v; }
    #pragma unroll
    for (int m = 8; m; m >>= 1) { s1 += __shfl_xor(s1,m); s2 += __shfl_xor(s2,m); }
    if (l16 == 0) {
      float mm = s1*(1.f/260.f);
      mu[tg] = mm;
      rstd[tg] = rsqrtf(s2*(1.f/260.f) - mm*mm + 1e-5f);
    }
  }
  __syncthreads();
  for (int dd = tid; dd < 260; dd += 256) {
    float g = pfc_g[dd], b = pfc_beta[dd];
    #pragma unroll
    for (int i = 0; i < 12; ++i) {
      float v = (zb[i][dd]-mu[i])*rstd[i]*g + b;
      float ge = 0.5f*v*(1.f + erff(v*0.70710678118654752f));
      ws[OFF_OUTS + (i*2048 + t)*260 + dd] = ge;
    }
  }
}

// ============ K5: fused LN + logits GEMM ============
__global__ __launch_bounds__(256) void k5_logits(
    const float* __restrict__ on_g, const float* __restrict__ on_b,
    const float* __restrict__ gain, float* __restrict__ ws,
    float* __restrict__ out) {
  int bid = blockIdx.x, tid = threadIdx.x;
  __shared__ float nl[8][260];
  __shared__ float red[4];
  float gn = gain[0];
  float og0 = on_g[tid], ob0 = on_b[tid];
  float og1 = (tid < 4) ? on_g[256+tid] : 0.f;
  float ob1 = (tid < 4) ? on_b[256+tid] : 0.f;
  for (int ii = 0; ii < 8; ++ii) {
    int m = bid*8 + ii;
    const float* row = ws + OFF_OUTS + m*260;
    float v0 = row[tid];
    float v1 = (tid < 4) ? row[256+tid] : 0.f;
    float s1 = block_sum256(v0 + v1, red);
    float s2 = block_sum256(v0*v0 + v1*v1, red);
    float mm = s1*(1.f/260.f);
    float rs = rsqrtf(s2*(1.f/260.f) - mm*mm + 1e-5f);
    nl[ii][tid] = (v0-mm)*rs*og0 + ob0;
    if (tid < 4) nl[ii][256+tid] = (v1-mm)*rs*og1 + ob1;
  }
  __syncthreads();
  float acc[8];
  #pragma unroll
  for (int ii = 0; ii < 8; ++ii) acc[ii] = 0.f;
  const float* st = ws + OFF_SNT;
  for (int k = 0; k < 260; ++k) {
    float wv = st[k*256 + tid];
    #pragma unroll
    for (int ii = 0; ii < 8; ++ii) acc[ii] += nl[ii][k]*wv;
  }
  #pragma unroll
  for (int ii = 0; ii < 8; ++ii)
    out[(bid*8 + ii)*256 + tid] = acc[ii]*gn;
}

// ============================ launch ============================
extern "C" void kernel_launch(void* const* d_in, const int* in_sizes, int n_in,
                              void* d_out, int out_size, void* d_ws, size_t ws_size,
                              hipStream_t stream) {
  const int*   x        = (const int*)  d_in[0];
  const float* h_f      = (const float*)d_in[1];
  const float* h_mono   = (const float*)d_in[2];
  const int*   surprise = (const int*)  d_in[3];
  const int*   dsteps   = (const int*)  d_in[4];
  const float* soma_w   = (const float*)d_in[5];
  const float* gWih     = (const float*)d_in[6];
  const float* gWhh     = (const float*)d_in[7];
  const float* gbih     = (const float*)d_in[8];
  const float* gbhh     = (const float*)d_in[9];
  const float* wWih     = (const float*)d_in[10];
  const float* wWhh     = (const float*)d_in[11];
  const float* wbih     = (const float*)d_in[12];
  const float* wbhh     = (const float*)d_in[13];
  const float* vgW      = (const float*)d_in[14];
  const float* vgb      = (const float*)d_in[15];
  const float* rel_keys = (const float*)d_in[16];
  const float* rel_vals = (const float*)d_in[17];
  const float* pfc_W    = (const float*)d_in[18];
  const float* pfc_b    = (const float*)d_in[19];
  const float* pfc_g    = (const float*)d_in[20];
  const float* pfc_beta = (const float*)d_in[21];
  const float* on_g     = (const float*)d_in[22];
  const float* on_b     = (const float*)d_in[23];
  const float* gain     = (const float*)d_in[24];
  float* out = (float*)d_out;
  float* ws  = (float*)d_ws;
  if (ws_size < (size_t)WS_FLOATS * sizeof(float)) return;  // fail loudly (poisoned out)
  int*   ctl      = (int*)(ws + OFF_OUTS);       // dead during scans; k4 rewrites
  float* will_acc = ws + OFF_WILL;
  hipMemsetAsync(ctl, 0, CTL_INTS*sizeof(int), stream);
  hipMemsetAsync(ws + OFF_HMT, 0, (size_t)(WS_FLOATS - OFF_HMT)*sizeof(float), stream);
  k0_prep  <<<1312, 256, 0, stream>>>(soma_w, gWih, gbih, rel_keys, pfc_W, ws);
  k23_scans<<<168, 1024, 0, stream>>>(x, h_f, gWhh, gbhh, h_mono, wWih, wWhh,
                                      wbih, wbhh, vgW, vgb, surprise, dsteps,
                                      ws, ctl, will_acc, out);
  k4_tail  <<<2048, 256, 0, stream>>>(rel_vals, pfc_b, pfc_g, pfc_beta,
                                      dsteps, will_acc, ws, out);
  k5_logits<<<3072, 256, 0, stream>>>(on_g, on_b, gain, ws, out);
}